// Round 3
// baseline (39.633 us; speedup 1.0000x reference)
//
#include <hip/hip_runtime.h>
#include <math.h>

#define NEXP 16
#define TOK_PER_THREAD 4
#define BLOCK 256

__global__ __launch_bounds__(BLOCK) void sparsemixer_kernel(
    const float* __restrict__ logits, float* __restrict__ out, int n_tok) {
    int base = blockIdx.x * (BLOCK * TOK_PER_THREAD) + threadIdx.x;

    // ---- issue ALL loads first: 4 rows x 4 float4 = 16 outstanding dwordx4/lane
    float x[TOK_PER_THREAD][NEXP];
    const float4* rows = reinterpret_cast<const float4*>(logits);
#pragma unroll
    for (int k = 0; k < TOK_PER_THREAD; ++k) {
        int t = base + k * BLOCK;
        if (t < n_tok) {
            const float4* row = rows + (size_t)t * 4;
#pragma unroll
            for (int q = 0; q < 4; ++q) {
                float4 v = row[q];
                x[k][4 * q + 0] = v.x;
                x[k][4 * q + 1] = v.y;
                x[k][4 * q + 2] = v.z;
                x[k][4 * q + 3] = v.w;
            }
        }
    }

    float2* oidx = reinterpret_cast<float2*>(out);
    float2* oval = reinterpret_cast<float2*>(out) + n_tok;

#pragma unroll
    for (int k = 0; k < TOK_PER_THREAD; ++k) {
        int t = base + k * BLOCK;
        if (t >= n_tok) continue;

        // single-scan top-2 with first-index tie semantics (strict >)
        float m0 = x[k][0], m1 = -INFINITY;
        int mi0 = 0, mi1 = 0;
#pragma unroll
        for (int j = 1; j < NEXP; ++j) {
            float v = x[k][j];
            if (v > m0) { m1 = m0; mi1 = mi0; m0 = v; mi0 = j; }
            else if (v > m1) { m1 = v; mi1 = j; }
        }

        // masked softmax denominators; divide-free mask test:
        //   (m-x)/max(|x|,m) > 0.02  <=>  (m-x) > 0.02*max(|x|,m)
        //   [den>=0 always; den==0 => ref NaN => kept; here 0>0 false => kept]
        float sum0 = 0.f, sum1 = 0.f;
#pragma unroll
        for (int j = 0; j < NEXP; ++j) {
            float v = x[k][j];
            float d0 = fmaxf(fabsf(v), m0);
            bool masked0 = (m0 - v) > 0.02f * d0;
            sum0 += masked0 ? 0.f : __expf(v - m0);
            float d1 = fmaxf(fabsf(v), m1);
            bool masked1 = (j == mi0) || ((m1 - v) > 0.02f * d1);
            sum1 += masked1 ? 0.f : __expf(v - m1);
        }
        float v0 = __builtin_amdgcn_rcpf(sum0);
        float v1 = __builtin_amdgcn_rcpf(sum1);

        oidx[t] = make_float2((float)mi0, (float)mi1);
        oval[t] = make_float2(v0, v1);
    }
}

extern "C" void kernel_launch(void* const* d_in, const int* in_sizes, int n_in,
                              void* d_out, int out_size, void* d_ws, size_t ws_size,
                              hipStream_t stream) {
    const float* logits = (const float*)d_in[0];
    float* out = (float*)d_out;
    int n_tok = in_sizes[0] / NEXP;
    int per_block = BLOCK * TOK_PER_THREAD;
    int grid = (n_tok + per_block - 1) / per_block;
    sparsemixer_kernel<<<grid, BLOCK, 0, stream>>>(logits, out, n_tok);
}

// Round 4
// 30.765 us; speedup vs baseline: 1.2883x; 1.2883x over previous
//
#include <hip/hip_runtime.h>
#include <math.h>

#define NEXP 16
#define BLOCK 256

__global__ __launch_bounds__(BLOCK) void sparsemixer_kernel(
    const float* __restrict__ logits, float* __restrict__ out, int n_tok) {
    int t = blockIdx.x * BLOCK + threadIdx.x;
    if (t >= n_tok) return;

    // Load the 16-logit row into registers (4 x float4 = 64B per lane, coalesced).
    float x[NEXP];
    const float4* row = reinterpret_cast<const float4*>(logits + (size_t)t * NEXP);
#pragma unroll
    for (int q = 0; q < 4; ++q) {
        float4 v = row[q];
        x[4 * q + 0] = v.x;
        x[4 * q + 1] = v.y;
        x[4 * q + 2] = v.z;
        x[4 * q + 3] = v.w;
    }

    // Single-scan top-2 with first-index tie semantics (strict >).
    float m0 = x[0], m1 = -INFINITY;
    int mi0 = 0, mi1 = 0;
#pragma unroll
    for (int j = 1; j < NEXP; ++j) {
        float v = x[j];
        if (v > m0) { m1 = m0; mi1 = mi0; m0 = v; mi0 = j; }
        else if (v > m1) { m1 = v; mi1 = j; }
    }

    // Masked softmax denominators with a single shared exp per expert:
    //   e_j = exp(x_j - m0);  sum1_shifted = sum_{kept1} e_j = exp(m1-m0)*sum1
    //   => v1 = exp(m1-m0) / sum1_shifted.
    // Mask arithmetic is EXACTLY the R2 form (bit-identical decisions):
    //   masked = (m - v) > 0.02f * fmax(|v|, m); den==0 -> 0>0 false -> kept
    //   (reference gets NaN there -> kept; identical).
    // The mi0 slot in pass 1 is never rel-masked (m1 <= m0 => diff <= 0) and
    // contributes e_{mi0} = exp(0) = 1 exactly -> sum unconditionally, then
    // subtract 1.0 (replaces the per-j  j != mi0  test).
    float s0a = 0.f, s0b = 0.f, s1a = 0.f, s1b = 0.f;
#pragma unroll
    for (int j = 0; j < NEXP; ++j) {
        float v = x[j];
        float ev = __expf(v - m0);
        float d0 = fmaxf(fabsf(v), m0);
        bool masked0 = (m0 - v) > 0.02f * d0;
        float d1 = fmaxf(fabsf(v), m1);
        bool masked1 = (m1 - v) > 0.02f * d1;
        if (j & 1) {
            s0b += masked0 ? 0.f : ev;
            s1b += masked1 ? 0.f : ev;
        } else {
            s0a += masked0 ? 0.f : ev;
            s1a += masked1 ? 0.f : ev;
        }
    }
    float sum0 = s0a + s0b;
    float sum1 = (s1a + s1b) - 1.0f;   // remove the mi0 term (exactly 1.0)
    float v0 = __builtin_amdgcn_rcpf(sum0);
    float v1 = __expf(m1 - m0) * __builtin_amdgcn_rcpf(sum1);

    // Outputs: [N,2] indices (as float), then [N,2] values.
    float2* oidx = reinterpret_cast<float2*>(out);
    float2* oval = reinterpret_cast<float2*>(out) + n_tok;
    oidx[t] = make_float2((float)mi0, (float)mi1);
    oval[t] = make_float2(v0, v1);
}

extern "C" void kernel_launch(void* const* d_in, const int* in_sizes, int n_in,
                              void* d_out, int out_size, void* d_ws, size_t ws_size,
                              hipStream_t stream) {
    const float* logits = (const float*)d_in[0];
    float* out = (float*)d_out;
    int n_tok = in_sizes[0] / NEXP;
    int grid = (n_tok + BLOCK - 1) / BLOCK;
    sparsemixer_kernel<<<grid, BLOCK, 0, stream>>>(logits, out, n_tok);
}